// Round 3
// baseline (368.680 us; speedup 1.0000x reference)
//
#include <hip/hip_runtime.h>

#define KK 64
#define TT 1024
#define BB 256
#define START_TAG 0

__device__ __forceinline__ float lane_bcast(float v, int lane) {
    return __int_as_float(__builtin_amdgcn_readlane(__float_as_int(v), lane));
}

// ds_swizzle BitMode: offset = (xor_mask<<10) | (or_mask<<5) | and_mask.
// and=0x1F, or=0, xor=k  ->  lane i reads lane (i^k) within its 32-lane half.
#define XORMASK(k) (((k) << 10) | 0x1F)
#define SWZ(v, k) __int_as_float(__builtin_amdgcn_ds_swizzle(__float_as_int(v), XORMASK(k)))

// et[k] = exp(trans[i][i ^ k]) — XOR-skewed layout so that the value delivered
// by (chunk-XOR 4h via swizzle/bpermute) x (quad-XOR q via DPP quad_perm)
// multiplies the matching transition weight with a plain fmac.
#define DECL4(p,q,r,s) \
    float et##p = __expf(trow[i ^ p]), et##q = __expf(trow[i ^ q]), \
          et##r = __expf(trow[i ^ r]), et##s = __expf(trow[i ^ s]);

#define PIN4(p,q,r,s) \
    asm volatile("" : "+v"(et##p), "+v"(et##q), "+v"(et##r), "+v"(et##s));

// First chunk (h=0): initialize the 4 accumulator chains with muls.
// DPP quad_perm:[1,0,3,2]=xor1, [2,3,0,1]=xor2, [3,2,1,0]=xor3 (explicit maps).
#define MULQ(S) \
    acc0 = (S) * et0; \
    asm volatile("v_mul_f32 %0, %1, %2 quad_perm:[1,0,3,2] row_mask:0xf bank_mask:0xf" \
                 : "=v"(acc1) : "v"(S), "v"(et1)); \
    asm volatile("v_mul_f32 %0, %1, %2 quad_perm:[2,3,0,1] row_mask:0xf bank_mask:0xf" \
                 : "=v"(acc2) : "v"(S), "v"(et2)); \
    asm volatile("v_mul_f32 %0, %1, %2 quad_perm:[3,2,1,0] row_mask:0xf bank_mask:0xf" \
                 : "=v"(acc3) : "v"(S), "v"(et3));

// One chunk: source S = a[i ^ 4h] broadcast reg; 4 fmacs cover k=4h..4h+3.
#define FMAH(S, p,q,r,s) { \
    acc0 = fmaf((S), et##p, acc0); \
    asm volatile("v_fmac_f32 %0, %1, %2 quad_perm:[1,0,3,2] row_mask:0xf bank_mask:0xf" \
                 : "+v"(acc1) : "v"(S), "v"(et##q)); \
    asm volatile("v_fmac_f32 %0, %1, %2 quad_perm:[2,3,0,1] row_mask:0xf bank_mask:0xf" \
                 : "+v"(acc2) : "v"(S), "v"(et##r)); \
    asm volatile("v_fmac_f32 %0, %1, %2 quad_perm:[3,2,1,0] row_mask:0xf bank_mask:0xf" \
                 : "+v"(acc3) : "v"(S), "v"(et##s)); }

// One recurrence step, single wave, everything in registers:
//  - 7 independent ds_swizzle (xor 4,8,...,28) on a
//  - 1 ds_bpermute (^32, precomputed address), then 7 swizzles of that
//    (xor 4..28 -> ^36..^60); issued mid-stream so the bpermute has returned
//  - 64 quad_perm-DPP fmacs on 4 chains, identity-chunk first (fills the
//    ~50-cycle swizzle latency with useful issue)
//  - tree sum, * exp(feat), mask select, optional renorm
//  - s_nop 1 pinned to a: VALU-write -> DPP-read hazard guard (compiler does
//    not insert wait states around inline-asm DPP)
#define DO_STEP(EFV, MKV, RN) { \
    float av = a; \
    float s1 = SWZ(av, 4),  s2 = SWZ(av, 8),  s3 = SWZ(av, 12), s4 = SWZ(av, 16); \
    float s5 = SWZ(av, 20), s6 = SWZ(av, 24), s7 = SWZ(av, 28); \
    float s8 = __int_as_float(__builtin_amdgcn_ds_bpermute(addr32, __float_as_int(av))); \
    float acc0, acc1, acc2, acc3; \
    MULQ(av) \
    FMAH(s1, 4,5,6,7)     FMAH(s2, 8,9,10,11)   FMAH(s3, 12,13,14,15) \
    FMAH(s4, 16,17,18,19) FMAH(s5, 20,21,22,23) FMAH(s6, 24,25,26,27) \
    FMAH(s7, 28,29,30,31) \
    float s9  = SWZ(s8, 4),  s10 = SWZ(s8, 8),  s11 = SWZ(s8, 12); \
    float s12 = SWZ(s8, 16), s13 = SWZ(s8, 20), s14 = SWZ(s8, 24); \
    float s15 = SWZ(s8, 28); \
    FMAH(s8,  32,33,34,35) FMAH(s9,  36,37,38,39) FMAH(s10, 40,41,42,43) \
    FMAH(s11, 44,45,46,47) FMAH(s12, 48,49,50,51) FMAH(s13, 52,53,54,55) \
    FMAH(s14, 56,57,58,59) FMAH(s15, 60,61,62,63) \
    float sum_ = (acc0 + acc1) + (acc2 + acc3); \
    float anew = sum_ * (EFV); \
    a = ((MKV) != 0.0f) ? anew : a; \
    if (RN) { \
        float a1 = fmaxf(lane_bcast(a, 1), 1e-37f); \
        a *= __builtin_amdgcn_rcpf(a1); \
        offset += __logf(a1); \
    } \
    asm volatile("s_nop 1" : "+v"(a)); \
}

// Forward algorithm in the probability domain. One wave per batch element;
// lane i owns state i. All cross-lane movement via XOR patterns:
// ds_swizzle (immediate) + one ds_bpermute + DPP quad_perm on the fmac.
// No LDS arrays, no barriers, no per-step readlane. Renorm once per 4 steps
// by a[1] (wave-uniform positive scale is exact via offset += log(scale)).
__global__ __launch_bounds__(64)
__attribute__((amdgpu_waves_per_eu(1, 1)))
void crf_forward_kernel(
    const float* __restrict__ feats,
    const float* __restrict__ trans,
    const float* __restrict__ masks,
    const int*   __restrict__ tags,
    float* __restrict__ out)
{
    const int b = blockIdx.x;
    const int i = threadIdx.x;
    const int addr32 = (i ^ 32) << 2;   // ds_bpermute byte address for lane^32

    const float* trow = trans + i * KK;
    DECL4(0,1,2,3)     DECL4(4,5,6,7)     DECL4(8,9,10,11)   DECL4(12,13,14,15)
    DECL4(16,17,18,19) DECL4(20,21,22,23) DECL4(24,25,26,27) DECL4(28,29,30,31)
    DECL4(32,33,34,35) DECL4(36,37,38,39) DECL4(40,41,42,43) DECL4(44,45,46,47)
    DECL4(48,49,50,51) DECL4(52,53,54,55) DECL4(56,57,58,59) DECL4(60,61,62,63)
    PIN4(0,1,2,3)     PIN4(4,5,6,7)     PIN4(8,9,10,11)   PIN4(12,13,14,15)
    PIN4(16,17,18,19) PIN4(20,21,22,23) PIN4(24,25,26,27) PIN4(28,29,30,31)
    PIN4(32,33,34,35) PIN4(36,37,38,39) PIN4(40,41,42,43) PIN4(44,45,46,47)
    PIN4(48,49,50,51) PIN4(52,53,54,55) PIN4(56,57,58,59) PIN4(60,61,62,63)

    float a = (i == START_TAG) ? 1.0f : 0.0f;  // exp(alpha0)
    float offset = 0.0f;                        // running log-scale
    asm volatile("s_nop 1" : "+v"(a));          // DPP hazard guard before 1st step

    const float* fb = feats + (size_t)b * TT * KK;
    const float* mb = masks + (size_t)b * TT;

    // prologue prefetch: steps t = 1..4
    float cf0 = fb[1 * KK + i], cf1 = fb[2 * KK + i];
    float cf2 = fb[3 * KK + i], cf3 = fb[4 * KK + i];
    float cm0 = mb[1], cm1 = mb[2], cm2 = mb[3], cm3 = mb[4];

    // groups t0 = 1,5,...,1021; last group's 4th step (t=1024) masked off
    for (int t0 = 1; t0 < TT; t0 += 4) {
        int p0 = (t0 + 4 < TT) ? t0 + 4 : TT - 1;
        int p1 = (t0 + 5 < TT) ? t0 + 5 : TT - 1;
        int p2 = (t0 + 6 < TT) ? t0 + 6 : TT - 1;
        int p3 = (t0 + 7 < TT) ? t0 + 7 : TT - 1;
        float nf0 = fb[p0 * KK + i], nf1 = fb[p1 * KK + i];
        float nf2 = fb[p2 * KK + i], nf3 = fb[p3 * KK + i];
        float nm0 = mb[p0], nm1 = mb[p1], nm2 = mb[p2], nm3 = mb[p3];

        // exp(feat): inputs prefetched a full group ago -> off critical path
        float ef0 = __expf(cf0), ef1 = __expf(cf1);
        float ef2 = __expf(cf2), ef3 = __expf(cf3);

        DO_STEP(ef0, cm0, 0)
        DO_STEP(ef1, cm1, 0)
        DO_STEP(ef2, cm2, 0)
        float m3 = (t0 + 3 < TT) ? cm3 : 0.0f;   // only last group clips
        DO_STEP(ef3, m3, 1)                       // renorm folded into step 4

        cf0 = nf0; cf1 = nf1; cf2 = nf2; cf3 = nf3;
        cm0 = nm0; cm1 = nm1; cm2 = nm2; cm3 = nm3;
    }

    // forward_score = offset + log(sum_j a_j)
    float s = a;
    #pragma unroll
    for (int off = 32; off >= 1; off >>= 1)
        s += __shfl_xor(s, off, 64);
    float fwd_score = offset + __logf(s);

    // ---- fused gold score: sum_t (trans[ct,pt] + feats[t,ct]) * mask[t] ----
    const int* tg = tags + b * TT;
    float g = 0.f;
    for (int t = 1 + i; t < TT; t += 64) {
        int ct = tg[t], pt = tg[t - 1];
        g += (trans[ct * KK + pt] + fb[t * KK + ct]) * mb[t];
    }
    #pragma unroll
    for (int off = 32; off >= 1; off >>= 1)
        g += __shfl_xor(g, off, 64);

    if (i == 0) atomicAdd(out, (fwd_score - g) * (1.0f / (float)BB));
}

extern "C" void kernel_launch(void* const* d_in, const int* in_sizes, int n_in,
                              void* d_out, int out_size, void* d_ws, size_t ws_size,
                              hipStream_t stream) {
    const float* feats = (const float*)d_in[0];
    const float* trans = (const float*)d_in[1];
    const int*   tags  = (const int*)d_in[2];
    const float* masks = (const float*)d_in[3];
    float* out = (float*)d_out;

    hipMemsetAsync(out, 0, sizeof(float), stream);  // atomicAdd accumulator
    crf_forward_kernel<<<BB, 64, 0, stream>>>(feats, trans, masks, tags, out);
}

// Round 4
// 297.772 us; speedup vs baseline: 1.2381x; 1.2381x over previous
//
#include <hip/hip_runtime.h>

#define KK 64
#define TT 1024
#define BB 256
#define START_TAG 0

typedef float v2f __attribute__((ext_vector_type(2)));
typedef float v4f __attribute__((ext_vector_type(4)));

__device__ __forceinline__ float lane_bcast(float v, int lane) {
    return __int_as_float(__builtin_amdgcn_readlane(__float_as_int(v), lane));
}

// Packed dual-fp32 VALU ops (CDNA3+/gfx950 VOP3P). Non-volatile asm with
// register-only constraints: the scheduler may interleave these freely with
// the ds_read lgkmcnt waits. Default VOP3P modifiers = lo*lo, hi*hi.
#define PKMUL(D, S, E) asm("v_pk_mul_f32 %0, %1, %2"     : "=v"(D) : "v"(S), "v"(E));
#define PKFMA(D, S, E) asm("v_pk_fma_f32 %0, %1, %2, %0" : "+v"(D) : "v"(S), "v"(E));
#define PKADD(D, X, Y) asm("v_pk_add_f32 %0, %1, %2"     : "=v"(D) : "v"(X), "v"(Y));

// et pair k: (exp(trans[i][2k]), exp(trans[i][2k+1])) — one v2f per 2 states,
// 32 pairs = 64 VGPRs, pinned so the compiler cannot rematerialize.
#define DECLP(k) v2f et##k = { __expf(trow[2*(k)]), __expf(trow[2*(k)+1]) };
#define PINP(p,q,r,s) asm volatile("" : "+v"(et##p), "+v"(et##q), "+v"(et##r), "+v"(et##s));

// One recurrence step, single wave, ~48 instructions total:
//   1 ds_write_b32 (scatter a[i]; 2-way bank alias = free)
//  16 ds_read_b128 (all lanes read the SAME address = conflict-free broadcast,
//     4 floats = 2 pairs per instruction)
//  16 v_pk_fma/pk_mul (64 MACs) + 3 pk_add + 1 add + scale + select
// No barrier, no double buffer: LDS ops of a single wave execute IN ORDER,
// so the wave's own write is visible to its subsequent reads; lgkmcnt only
// gates VALU consumption of read data (compiler inserts fine-grained waits).
#define DO_STEP(EFV, MKV, RN) { \
    abuf[i] = a; \
    const v4f* rb_ = reinterpret_cast<const v4f*>(abuf); \
    v4f w0 = rb_[0],  w1 = rb_[1],  w2 = rb_[2],  w3 = rb_[3]; \
    v4f w4 = rb_[4],  w5 = rb_[5],  w6 = rb_[6],  w7 = rb_[7]; \
    v4f w8 = rb_[8],  w9 = rb_[9],  w10 = rb_[10], w11 = rb_[11]; \
    v4f w12 = rb_[12], w13 = rb_[13], w14 = rb_[14], w15 = rb_[15]; \
    v2f acc0, acc1, acc2, acc3; \
    PKMUL(acc0, w0.xy, et0)   PKMUL(acc1, w0.zw, et1) \
    PKMUL(acc2, w1.xy, et2)   PKMUL(acc3, w1.zw, et3) \
    PKFMA(acc0, w2.xy, et4)   PKFMA(acc1, w2.zw, et5) \
    PKFMA(acc2, w3.xy, et6)   PKFMA(acc3, w3.zw, et7) \
    PKFMA(acc0, w4.xy, et8)   PKFMA(acc1, w4.zw, et9) \
    PKFMA(acc2, w5.xy, et10)  PKFMA(acc3, w5.zw, et11) \
    PKFMA(acc0, w6.xy, et12)  PKFMA(acc1, w6.zw, et13) \
    PKFMA(acc2, w7.xy, et14)  PKFMA(acc3, w7.zw, et15) \
    PKFMA(acc0, w8.xy, et16)  PKFMA(acc1, w8.zw, et17) \
    PKFMA(acc2, w9.xy, et18)  PKFMA(acc3, w9.zw, et19) \
    PKFMA(acc0, w10.xy, et20) PKFMA(acc1, w10.zw, et21) \
    PKFMA(acc2, w11.xy, et22) PKFMA(acc3, w11.zw, et23) \
    PKFMA(acc0, w12.xy, et24) PKFMA(acc1, w12.zw, et25) \
    PKFMA(acc2, w13.xy, et26) PKFMA(acc3, w13.zw, et27) \
    PKFMA(acc0, w14.xy, et28) PKFMA(acc1, w14.zw, et29) \
    PKFMA(acc2, w15.xy, et30) PKFMA(acc3, w15.zw, et31) \
    v2f accA, accB, accC; \
    PKADD(accA, acc0, acc1) \
    PKADD(accB, acc2, acc3) \
    PKADD(accC, accA, accB) \
    float s_ = accC.x + accC.y; \
    float anew = s_ * (EFV); \
    a = ((MKV) != 0.0f) ? anew : a; \
    if (RN) { \
        float a1 = fmaxf(lane_bcast(a, 1), 1e-37f); \
        a *= __builtin_amdgcn_rcpf(a1); \
        offset += __logf(a1); \
    } \
}

// Forward algorithm in the probability domain. One wave per batch element;
// lane i owns state i, et pairs hold exp(trans[i][2k..2k+1]). The wave is
// issue-cadence-bound (~1 inst / 4-5 cyc at 1 wave/SIMD across rounds 0-3),
// so the design minimizes instructions/step: packed-fp32 FMAs + b128 LDS
// broadcast. Renorm once per 4 steps by a[1] (wave-uniform positive scale
// is exact via offset += log(scale)).
__global__ __launch_bounds__(64)
__attribute__((amdgpu_waves_per_eu(1, 1)))
void crf_forward_kernel(
    const float* __restrict__ feats,
    const float* __restrict__ trans,
    const float* __restrict__ masks,
    const int*   __restrict__ tags,
    float* __restrict__ out)
{
    const int b = blockIdx.x;
    const int i = threadIdx.x;

    __shared__ __align__(16) float abuf[KK];

    const float* trow = trans + i * KK;
    DECLP(0)  DECLP(1)  DECLP(2)  DECLP(3)  DECLP(4)  DECLP(5)  DECLP(6)  DECLP(7)
    DECLP(8)  DECLP(9)  DECLP(10) DECLP(11) DECLP(12) DECLP(13) DECLP(14) DECLP(15)
    DECLP(16) DECLP(17) DECLP(18) DECLP(19) DECLP(20) DECLP(21) DECLP(22) DECLP(23)
    DECLP(24) DECLP(25) DECLP(26) DECLP(27) DECLP(28) DECLP(29) DECLP(30) DECLP(31)
    PINP(0,1,2,3)     PINP(4,5,6,7)     PINP(8,9,10,11)   PINP(12,13,14,15)
    PINP(16,17,18,19) PINP(20,21,22,23) PINP(24,25,26,27) PINP(28,29,30,31)

    float a = (i == START_TAG) ? 1.0f : 0.0f;  // exp(alpha0)
    float offset = 0.0f;                        // running log-scale

    const float* fb = feats + (size_t)b * TT * KK;
    const float* mb = masks + (size_t)b * TT;

    // prologue prefetch: steps t = 1..4
    float cf0 = fb[1 * KK + i], cf1 = fb[2 * KK + i];
    float cf2 = fb[3 * KK + i], cf3 = fb[4 * KK + i];
    float cm0 = mb[1], cm1 = mb[2], cm2 = mb[3], cm3 = mb[4];

    // groups t0 = 1,5,...,1021; last group's 4th step (t=1024) masked off
    for (int t0 = 1; t0 < TT; t0 += 4) {
        int p0 = (t0 + 4 < TT) ? t0 + 4 : TT - 1;
        int p1 = (t0 + 5 < TT) ? t0 + 5 : TT - 1;
        int p2 = (t0 + 6 < TT) ? t0 + 6 : TT - 1;
        int p3 = (t0 + 7 < TT) ? t0 + 7 : TT - 1;
        float nf0 = fb[p0 * KK + i], nf1 = fb[p1 * KK + i];
        float nf2 = fb[p2 * KK + i], nf3 = fb[p3 * KK + i];
        float nm0 = mb[p0], nm1 = mb[p1], nm2 = mb[p2], nm3 = mb[p3];

        // exp(feat): inputs prefetched a full group ago -> off critical path
        float ef0 = __expf(cf0), ef1 = __expf(cf1);
        float ef2 = __expf(cf2), ef3 = __expf(cf3);

        DO_STEP(ef0, cm0, 0)
        DO_STEP(ef1, cm1, 0)
        DO_STEP(ef2, cm2, 0)
        float m3 = (t0 + 3 < TT) ? cm3 : 0.0f;   // only last group clips
        DO_STEP(ef3, m3, 1)                       // renorm folded into step 4

        cf0 = nf0; cf1 = nf1; cf2 = nf2; cf3 = nf3;
        cm0 = nm0; cm1 = nm1; cm2 = nm2; cm3 = nm3;
    }

    // forward_score = offset + log(sum_j a_j)
    float s = a;
    #pragma unroll
    for (int off = 32; off >= 1; off >>= 1)
        s += __shfl_xor(s, off, 64);
    float fwd_score = offset + __logf(s);

    // ---- fused gold score: sum_t (trans[ct,pt] + feats[t,ct]) * mask[t] ----
    const int* tg = tags + b * TT;
    float g = 0.f;
    for (int t = 1 + i; t < TT; t += 64) {
        int ct = tg[t], pt = tg[t - 1];
        g += (trans[ct * KK + pt] + fb[t * KK + ct]) * mb[t];
    }
    #pragma unroll
    for (int off = 32; off >= 1; off >>= 1)
        g += __shfl_xor(g, off, 64);

    if (i == 0) atomicAdd(out, (fwd_score - g) * (1.0f / (float)BB));
}

extern "C" void kernel_launch(void* const* d_in, const int* in_sizes, int n_in,
                              void* d_out, int out_size, void* d_ws, size_t ws_size,
                              hipStream_t stream) {
    const float* feats = (const float*)d_in[0];
    const float* trans = (const float*)d_in[1];
    const int*   tags  = (const int*)d_in[2];
    const float* masks = (const float*)d_in[3];
    float* out = (float*)d_out;

    hipMemsetAsync(out, 0, sizeof(float), stream);  // atomicAdd accumulator
    crf_forward_kernel<<<BB, 64, 0, stream>>>(feats, trans, masks, tags, out);
}